// Round 19
// baseline (143.041 us; speedup 1.0000x reference)
//
#include <hip/hip_runtime.h>
#include <hip/hip_bf16.h>
#include <stdint.h>

#define B_N 4
#define NQ 1024
#define NKV 2048
#define DI 1024
#define H 16
#define DH 64

using bf16 = __bf16;
typedef bf16 bf16x8 __attribute__((ext_vector_type(8)));
typedef bf16 bf16x4 __attribute__((ext_vector_type(4)));
typedef float f32x4 __attribute__((ext_vector_type(4)));

typedef const __attribute__((address_space(1))) void* gptr_t;
typedef __attribute__((address_space(3))) void* sptr_t;

// ---------- fused prep: LayerNorm (blocks 0..12287) + weight f32->bf16 (12288..16383) ----------
__global__ __launch_bounds__(256) void prep_kernel(
    const float* __restrict__ q, const float* __restrict__ ctx,
    const float* __restrict__ qg, const float* __restrict__ qb,
    const float* __restrict__ cg, const float* __restrict__ cb,
    bf16* __restrict__ qn, bf16* __restrict__ cn,
    const float* __restrict__ Wq, const float* __restrict__ Wkv, const float* __restrict__ Wproj,
    bf16* __restrict__ oq, bf16* __restrict__ okv, bf16* __restrict__ op) {
  const int blk = blockIdx.x;
  const int t = threadIdx.x;
  if (blk >= 12288) {   // ---- weight convert: 1M float4 over 4096 blocks ----
    int i = (blk - 12288) * 256 + t;
    const float* src; bf16* dst; int j;
    if (i < 262144)      { src = Wq;    dst = oq;  j = i; }
    else if (i < 786432) { src = Wkv;   dst = okv; j = i - 262144; }
    else                 { src = Wproj; dst = op;  j = i - 786432; }
    float4 v = reinterpret_cast<const float4*>(src)[j];
    bf16x4 o;
    o[0] = (bf16)v.x; o[1] = (bf16)v.y; o[2] = (bf16)v.z; o[3] = (bf16)v.w;
    reinterpret_cast<bf16x4*>(dst)[j] = o;
    return;
  }
  // ---- LayerNorm: one row per block ----
  const float* x; const float* gamma; const float* beta; bf16* out; int r;
  if (blk < 4096) { x = q;   gamma = qg; beta = qb; out = qn; r = blk; }
  else            { x = ctx; gamma = cg; beta = cb; out = cn; r = blk - 4096; }
  const float4 v = reinterpret_cast<const float4*>(x + (size_t)r * 1024)[t];
  float s = v.x + v.y + v.z + v.w;
  float s2 = v.x*v.x + v.y*v.y + v.z*v.z + v.w*v.w;
#pragma unroll
  for (int m = 1; m < 64; m <<= 1) { s += __shfl_xor(s, m); s2 += __shfl_xor(s2, m); }
  __shared__ float red[8];
  int wid = t >> 6;
  if ((t & 63) == 0) { red[wid] = s; red[wid + 4] = s2; }
  __syncthreads();
  float ts  = red[0] + red[1] + red[2] + red[3];
  float ts2 = red[4] + red[5] + red[6] + red[7];
  float mean = ts * (1.0f / 1024.0f);
  float var  = ts2 * (1.0f / 1024.0f) - mean * mean;
  float rstd = rsqrtf(var + 1e-5f);
  float4 g  = reinterpret_cast<const float4*>(gamma)[t];
  float4 bb = reinterpret_cast<const float4*>(beta)[t];
  bf16x4 o;
  o[0] = (bf16)((v.x - mean) * rstd * g.x + bb.x);
  o[1] = (bf16)((v.y - mean) * rstd * g.y + bb.y);
  o[2] = (bf16)((v.z - mean) * rstd * g.z + bb.z);
  o[3] = (bf16)((v.w - mean) * rstd * g.w + bb.w);
  reinterpret_cast<bf16x4*>(out + (size_t)r * 1024)[t] = o;
}

// ======== gemm_fused body: 128x128, BK=64, counted-vmcnt double-buffer ========
// Per K-step: raw s_barrier -> STAGE(next buf, 8 loads) -> s_waitcnt vmcnt(8)
// (prev step's loads landed; this step's stay in flight) -> 16 ds_read + 32 MFMA.
// Race-free: stage into buf^1 occurs after the barrier; all waves' reads of buf^1
// completed before reaching that barrier. XOR swizzle sw=l15&7 (0-conflict, proven).
// MODE 0: bf16 out * (0.125*log2e) | MODE 1: kv split K + V^T-permuted
template<int MODE>
__device__ __forceinline__ void gemm_db_body(bf16* lA, bf16* lB,
    const bf16* __restrict__ A, const bf16* __restrict__ Bm,
    void* __restrict__ out0, void* __restrict__ out1, int N, int bid) {
  constexpr int K = 1024;
  const int nbn = N >> 7;
  const int bm = bid / nbn, bn = bid - bm * nbn;
  const int m0 = bm << 7, n0 = bn << 7;
  const int tid = threadIdx.x;
  const int lane = tid & 63, wid = tid >> 6;
  const int rowb = (wid >> 1) * 64, colb = (wid & 1) * 64;
  const int l15 = lane & 15, lg = lane >> 4;

  f32x4 acc[4][4] = {};

  const bf16* gA[4]; const bf16* gB[4];
#pragma unroll
  for (int u = 0; u < 4; ++u) {
    int s = tid + u * 256;
    int row = s >> 3, c8 = (s & 7) ^ (row & 7);
    gA[u] = A + (size_t)(m0 + row) * K + c8 * 8;
    gB[u] = Bm + (size_t)(n0 + row) * K + c8 * 8;
  }
  const int sw = l15 & 7;

#define DBSTAGE(buf, k0)                                                                             \
  do {                                                                                               \
    _Pragma("unroll")                                                                                \
    for (int u = 0; u < 4; ++u)                                                                      \
      __builtin_amdgcn_global_load_lds((gptr_t)(gA[u] + (k0)),                                       \
          (sptr_t)(lA + (buf) * 8192 + (tid + u * 256) * 8), 16, 0, 0);                              \
    _Pragma("unroll")                                                                                \
    for (int u = 0; u < 4; ++u)                                                                      \
      __builtin_amdgcn_global_load_lds((gptr_t)(gB[u] + (k0)),                                       \
          (sptr_t)(lB + (buf) * 8192 + (tid + u * 256) * 8), 16, 0, 0);                              \
  } while (0)

  DBSTAGE(0, 0);

  for (int kt = 0; kt < 16; ++kt) {
    const int cur = kt & 1;
    __builtin_amdgcn_s_barrier();
    if (kt < 15) {
      DBSTAGE(cur ^ 1, (kt + 1) * 64);
      asm volatile("s_waitcnt vmcnt(8)" ::: "memory");
    } else {
      asm volatile("s_waitcnt vmcnt(0)" ::: "memory");
    }
    const bf16* lAc = lA + cur * 8192;
    const bf16* lBc = lB + cur * 8192;
#pragma unroll
    for (int ks2 = 0; ks2 < 2; ++ks2) {
      const int soff = ((ks2 * 4 + lg) ^ sw) * 8;
      bf16x8 af[4], bfr[4];
#pragma unroll
      for (int i = 0; i < 4; ++i)
        af[i]  = *reinterpret_cast<const bf16x8*>(lAc + (rowb + i * 16 + l15) * 64 + soff);
#pragma unroll
      for (int j = 0; j < 4; ++j)
        bfr[j] = *reinterpret_cast<const bf16x8*>(lBc + (colb + j * 16 + l15) * 64 + soff);
      __builtin_amdgcn_s_setprio(1);
#pragma unroll
      for (int i = 0; i < 4; ++i)
#pragma unroll
        for (int j = 0; j < 4; ++j)
          acc[i][j] = __builtin_amdgcn_mfma_f32_16x16x32_bf16(af[i], bfr[j], acc[i][j], 0, 0, 0);
      __builtin_amdgcn_s_setprio(0);
    }
  }
#undef DBSTAGE

  const int mB = m0 + rowb + lg * 4;
  const int nB = n0 + colb + l15;
  if constexpr (MODE == 0) {
    bf16* o = reinterpret_cast<bf16*>(out0);
    constexpr float SC = 0.125f * 1.44269504089f;  // DH^-0.5 * log2(e)
#pragma unroll
    for (int i = 0; i < 4; ++i)
#pragma unroll
      for (int j = 0; j < 4; ++j)
#pragma unroll
        for (int r = 0; r < 4; ++r)
          o[(size_t)(mB + i * 16 + r) * N + nB + j * 16] = (bf16)(acc[i][j][r] * SC);
  } else {
    if (n0 < 1024) {  // K part: (B,NKV,DI)
      bf16* o = reinterpret_cast<bf16*>(out0);
#pragma unroll
      for (int i = 0; i < 4; ++i)
#pragma unroll
        for (int j = 0; j < 4; ++j)
#pragma unroll
          for (int r = 0; r < 4; ++r)
            o[(size_t)(mB + i * 16 + r) * 1024 + nB + j * 16] = (bf16)acc[i][j][r];
    } else {          // V part: transposed (B,DI,NKV) with in-64 column swizzle
      bf16* o = reinterpret_cast<bf16*>(out1);
#pragma unroll
      for (int i = 0; i < 4; ++i) {
        int m = mB + i * 16;
        int bb_ = m >> 11, kv = m & 2047;
        int u = kv & 63;
        int c = (u & 32) | ((u & 12) << 1) | ((u & 16) >> 2) | (u & 3);
        int col = (kv & ~63) | c;
#pragma unroll
        for (int j = 0; j < 4; ++j) {
          int nv = nB + j * 16 - 1024;
          bf16x4 pk;
          pk[0] = (bf16)acc[i][j][0]; pk[1] = (bf16)acc[i][j][1];
          pk[2] = (bf16)acc[i][j][2]; pk[3] = (bf16)acc[i][j][3];
          *reinterpret_cast<bf16x4*>(o + ((size_t)(bb_ << 10) + nv) * 2048 + col) = pk;
        }
      }
    }
  }
}

// Merged qp + kv GEMM: blocks [0,1024) = kv (MODE 1), [1024,1280) = qp (MODE 0).
__global__ __launch_bounds__(256) void gemm_fused(
    const bf16* __restrict__ qn, const bf16* __restrict__ Wq, void* __restrict__ qpb,
    const bf16* __restrict__ cn, const bf16* __restrict__ Wkv,
    void* __restrict__ kbuf, void* __restrict__ vT) {
  __shared__ bf16 lA[2 * 8192];   // 32 KB
  __shared__ bf16 lB[2 * 8192];   // 32 KB
  if (blockIdx.x < 1024) {
    int rb = blockIdx.x;
    int bid = (rb & 7) * 128 + (rb >> 3);
    gemm_db_body<1>(lA, lB, cn, Wkv, kbuf, vT, 2048, bid);
  } else {
    int rb = blockIdx.x - 1024;
    int bid = (rb & 7) * 32 + (rb >> 3);
    gemm_db_body<0>(lA, lB, qn, Wq, qpb, nullptr, 1024, bid);
  }
}

// ---------------- proj GEMM (r10-proven): 128 x 64, BK=64, 2-phase ----------------
__global__ __launch_bounds__(256) void gemm_proj(const bf16* __restrict__ A,
    const bf16* __restrict__ Bm, float* __restrict__ out0,
    const float* __restrict__ bias, int M, int N) {
  constexpr int K = 1024;
  __shared__ bf16 lA[128 * 64];
  __shared__ bf16 lB[64 * 64];
  const int cpx = gridDim.x >> 3;
  const int bid = (blockIdx.x & 7) * cpx + (blockIdx.x >> 3);
  const int nbn = N >> 6;
  const int bm = bid / nbn, bn = bid - bm * nbn;
  const int m0 = bm << 7, n0 = bn << 6;
  const int tid = threadIdx.x;
  const int lane = tid & 63, wid = tid >> 6;
  const int rowb = wid * 32;
  const int l15 = lane & 15, lg = lane >> 4;

  f32x4 acc[2][4] = {};

  const bf16* gA[4]; const bf16* gB[2];
#pragma unroll
  for (int u = 0; u < 4; ++u) {
    int s = tid + u * 256;
    int row = s >> 3, c8 = (s & 7) ^ (row & 7);
    gA[u] = A + (size_t)(m0 + row) * K + c8 * 8;
  }
#pragma unroll
  for (int u = 0; u < 2; ++u) {
    int s = tid + u * 256;
    int row = s >> 3, c8 = (s & 7) ^ (row & 7);
    gB[u] = Bm + (size_t)(n0 + row) * K + c8 * 8;
  }
  const int sw = l15 & 7;

  for (int k0 = 0; k0 < K; k0 += 64) {
#pragma unroll
    for (int u = 0; u < 4; ++u)
      __builtin_amdgcn_global_load_lds((gptr_t)(gA[u] + k0), (sptr_t)(lA + (tid + u * 256) * 8), 16, 0, 0);
#pragma unroll
    for (int u = 0; u < 2; ++u)
      __builtin_amdgcn_global_load_lds((gptr_t)(gB[u] + k0), (sptr_t)(lB + (tid + u * 256) * 8), 16, 0, 0);
    __syncthreads();
#pragma unroll
    for (int ks2 = 0; ks2 < 2; ++ks2) {
      const int soff = ((ks2 * 4 + lg) ^ sw) * 8;
      bf16x8 af[2], bfr[4];
#pragma unroll
      for (int i = 0; i < 2; ++i)
        af[i]  = *reinterpret_cast<const bf16x8*>(lA + (rowb + i * 16 + l15) * 64 + soff);
#pragma unroll
      for (int j = 0; j < 4; ++j)
        bfr[j] = *reinterpret_cast<const bf16x8*>(lB + (j * 16 + l15) * 64 + soff);
#pragma unroll
      for (int i = 0; i < 2; ++i)
#pragma unroll
        for (int j = 0; j < 4; ++j)
          acc[i][j] = __builtin_amdgcn_mfma_f32_16x16x32_bf16(af[i], bfr[j], acc[i][j], 0, 0, 0);
    }
    __syncthreads();
  }

  const int mB = m0 + rowb + lg * 4;
  const int nB = n0 + l15;
#pragma unroll
  for (int j = 0; j < 4; ++j) {
    float bj = bias[nB + j * 16];
#pragma unroll
    for (int i = 0; i < 2; ++i)
#pragma unroll
      for (int r = 0; r < 4; ++r)
        out0[(size_t)(mB + i * 16 + r) * N + nB + j * 16] = acc[i][j][r] + bj;
  }
}

// ---------------- Flash attention v9 (r17-proven): ones-MFMA row-sum + max3 tree ----------------
__global__ __launch_bounds__(512, 4) void attn_kernel(const bf16* __restrict__ qp,
    const bf16* __restrict__ kk, const bf16* __restrict__ vTp, bf16* __restrict__ out) {
  __shared__ bf16 smem[32768];   // [K dbuf 2x8192][V dbuf 2x8192]  (64 KB)
  const int pos = blockIdx.x;
  const int idx = pos >> 3;
  const int bh = ((idx >> 3) << 3) | (pos & 7);
  const int qt = idx & 7;
  const int b = bh >> 4, h = bh & 15;
  const int tid = threadIdx.x;              // 0..511
  const int lane = tid & 63, w = tid >> 6;  // 8 waves
  const int l15 = lane & 15, lg = lane >> 4;

  const bf16* Qb = qp + (size_t)(b * NQ + qt * 128 + w * 16) * DI + h * DH;
  const bf16* Kb = kk + (size_t)b * NKV * DI + h * DH;
  const bf16* Vb = vTp + (size_t)(b * DI + h * DH) * NKV;

  const int sA = tid, sB = tid + 512;
  const int rKA = ((sA >> 7) << 4) | (sA & 15), cKA = ((sA >> 4) & 7) * 8;
  const int rKB = ((sB >> 7) << 4) | (sB & 15), cKB = ((sB >> 4) & 7) * 8;
  const int rVA = ((sA >> 8) << 4) | (sA & 15), cVA = ((sA >> 6) & 3) * 32 + ((sA >> 4) & 3) * 8;
  const int rVB = ((sB >> 8) << 4) | (sB & 15), cVB = ((sB >> 6) & 3) * 32 + ((sB >> 4) & 3) * 8;
  const bf16* pKA = Kb + (size_t)rKA * DI + cKA;
  const bf16* pKB = Kb + (size_t)rKB * DI + cKB;
  const bf16* pVA = Vb + (size_t)rVA * NKV + cVA;
  const bf16* pVB = Vb + (size_t)rVB * NKV + cVB;

#define STAGE_KV(bufsel, kv)                                                                        \
  do {                                                                                              \
    __builtin_amdgcn_global_load_lds((gptr_t)(pKA + (size_t)(kv) * DI),                             \
                                     (sptr_t)(smem + (bufsel) * 8192 + sA * 8), 16, 0, 0);          \
    __builtin_amdgcn_global_load_lds((gptr_t)(pKB + (size_t)(kv) * DI),                             \
                                     (sptr_t)(smem + (bufsel) * 8192 + sB * 8), 16, 0, 0);          \
    __builtin_amdgcn_global_load_lds((gptr_t)(pVA + (kv)),                                          \
                                     (sptr_t)(smem + 16384 + (bufsel) * 8192 + sA * 8), 16, 0, 0);  \
    __builtin_amdgcn_global_load_lds((gptr_t)(pVB + (kv)),                                          \
                                     (sptr_t)(smem + 16384 + (bufsel) * 8192 + sB * 8), 16, 0, 0);  \
  } while (0)

  bf16x8 qf[2];
#pragma unroll
  for (int ks = 0; ks < 2; ++ks)
    qf[ks] = *reinterpret_cast<const bf16x8*>(Qb + (size_t)l15 * DI + ks * 32 + lg * 8);

  bf16x8 onesf;
#pragma unroll
  for (int jj = 0; jj < 8; ++jj) onesf[jj] = (bf16)1.0f;

  f32x4 o[4] = {};
  f32x4 lacc = {};
  float mrun = -1e30f;

  STAGE_KV(0, 0);
  __syncthreads();
  int cur = 0;

  for (int kv0 = 0; kv0 < NKV; kv0 += 128) {
    const bool notlast = (kv0 + 128 < NKV);
    if (notlast) STAGE_KV(cur ^ 1, kv0 + 128);

    const bf16* Kl = smem + cur * 8192;
    const bf16* Vl = smem + 16384 + cur * 8192;

    f32x4 s[8] = {};
#pragma unroll
    for (int h2 = 0; h2 < 2; ++h2) {
      bf16x8 kf[4][2];
#pragma unroll
      for (int ni = 0; ni < 4; ++ni)
#pragma unroll
        for (int ks = 0; ks < 2; ++ks)
          kf[ni][ks] = *reinterpret_cast<const bf16x8*>(Kl + (((h2 * 4 + ni) * 2 + ks) * 64 + lane) * 8);
      __builtin_amdgcn_s_setprio(1);
#pragma unroll
      for (int ni = 0; ni < 4; ++ni)
#pragma unroll
        for (int ks = 0; ks < 2; ++ks)
          s[h2 * 4 + ni] = __builtin_amdgcn_mfma_f32_16x16x32_bf16(kf[ni][ks], qf[ks], s[h2 * 4 + ni], 0, 0, 0);
      __builtin_amdgcn_s_setprio(0);
    }

    // ---- row max (max3-fused tree; per q = l15) ----
    float pmr[4];
#pragma unroll
    for (int r = 0; r < 4; ++r) {
      float a = fmaxf(fmaxf(s[0][r], s[1][r]), s[2][r]);
      a = fmaxf(fmaxf(a, s[3][r]), s[4][r]);
      a = fmaxf(fmaxf(a, s[5][r]), s[6][r]);
      pmr[r] = fmaxf(a, s[7][r]);
    }
    float pm = fmaxf(fmaxf(pmr[0], pmr[1]), fmaxf(pmr[2], pmr[3]));
    pm = fmaxf(pm, __shfl_xor(pm, 16));
    pm = fmaxf(pm, __shfl_xor(pm, 32));

    const bool noresc = __all(pm <= mrun);   // exact: corr == 1 when no new max
    const float mnew = noresc ? mrun : fmaxf(mrun, pm);

#pragma unroll
    for (int i = 0; i < 8; ++i)
#pragma unroll
      for (int r = 0; r < 4; ++r)
        s[i][r] = __builtin_amdgcn_exp2f(s[i][r] - mnew);

    if (!noresc) {
      float corr = __builtin_amdgcn_exp2f(mrun - mnew);
      mrun = mnew;
      float c0 = __shfl(corr, lg * 4 + 0);
      float c1 = __shfl(corr, lg * 4 + 1);
      float c2 = __shfl(corr, lg * 4 + 2);
      float c3 = __shfl(corr, lg * 4 + 3);
      lacc[0] *= c0; lacc[1] *= c1; lacc[2] *= c2; lacc[3] *= c3;
#pragma unroll
      for (int dt = 0; dt < 4; ++dt) {
        o[dt][0] *= c0; o[dt][1] *= c1; o[dt][2] *= c2; o[dt][3] *= c3;
      }
    }

    // ---- pack P (register-only): pa[k2], k2 = h2*2 + k2' ----
    bf16x8 pa[4];
#pragma unroll
    for (int h2 = 0; h2 < 2; ++h2)
#pragma unroll
      for (int k2p = 0; k2p < 2; ++k2p)
#pragma unroll
        for (int jj = 0; jj < 4; ++jj) {
          pa[h2 * 2 + k2p][jj]     = (bf16)s[h2 * 4 + k2p * 2 + 0][jj];
          pa[h2 * 2 + k2p][4 + jj] = (bf16)s[h2 * 4 + k2p * 2 + 1][jj];
        }

    // ---- PV + row-sum, all on the matrix pipe ----
    __builtin_amdgcn_s_setprio(1);
#pragma unroll
    for (int k2 = 0; k2 < 4; ++k2) {
      bf16x8 vf[4];
#pragma unroll
      for (int dt = 0; dt < 4; ++dt)
        vf[dt] = *reinterpret_cast<const bf16x8*>(Vl + ((dt * 4 + k2) * 64 + lane) * 8);
#pragma unroll
      for (int dt = 0; dt < 4; ++dt)
        o[dt] = __builtin_amdgcn_mfma_f32_16x16x32_bf16(pa[k2], vf[dt], o[dt], 0, 0, 0);
      lacc = __builtin_amdgcn_mfma_f32_16x16x32_bf16(pa[k2], onesf, lacc, 0, 0, 0);
    }
    __builtin_amdgcn_s_setprio(0);

    if (notlast) __syncthreads();
    cur ^= 1;
  }
#undef STAGE_KV

  // epilogue: lacc already holds per-(lg,r) row sums in O-layout -> no shuffles
  const float iv0 = 1.0f / lacc[0];
  const float iv1 = 1.0f / lacc[1];
  const float iv2 = 1.0f / lacc[2];
  const float iv3 = 1.0f / lacc[3];

  bf16* Ob = out + (size_t)(b * NQ + qt * 128 + w * 16) * DI + h * DH;
#pragma unroll
  for (int dt = 0; dt < 4; ++dt) {
    Ob[(size_t)(lg * 4 + 0) * DI + dt * 16 + l15] = (bf16)(o[dt][0] * iv0);
    Ob[(size_t)(lg * 4 + 1) * DI + dt * 16 + l15] = (bf16)(o[dt][1] * iv1);
    Ob[(size_t)(lg * 4 + 2) * DI + dt * 16 + l15] = (bf16)(o[dt][2] * iv2);
    Ob[(size_t)(lg * 4 + 3) * DI + dt * 16 + l15] = (bf16)(o[dt][3] * iv3);
  }
}

// ---------------- launch ----------------
extern "C" void kernel_launch(void* const* d_in, const int* in_sizes, int n_in,
                              void* d_out, int out_size, void* d_ws, size_t ws_size,
                              hipStream_t stream) {
  const float* q     = (const float*)d_in[0];
  const float* ctx   = (const float*)d_in[1];
  const float* Wq    = (const float*)d_in[2];
  const float* Wkv   = (const float*)d_in[3];
  const float* Wproj = (const float*)d_in[4];
  const float* bproj = (const float*)d_in[5];
  const float* qg    = (const float*)d_in[6];
  const float* qb    = (const float*)d_in[7];
  const float* cg    = (const float*)d_in[8];
  const float* cb    = (const float*)d_in[9];

  char* ws = (char*)d_ws;
  bf16* qn    = (bf16*)(ws);                       // 8 MB  (4096x1024)
  bf16* cn    = (bf16*)(ws + ( 8ull << 20));       // 16 MB (8192x1024)
  bf16* Wq_b  = (bf16*)(ws + (24ull << 20));       // 2 MB
  bf16* Wkv_b = (bf16*)(ws + (26ull << 20));       // 4 MB
  bf16* Wp_b  = (bf16*)(ws + (30ull << 20));       // 2 MB
  bf16* qpb   = (bf16*)(ws + (32ull << 20));       // 8 MB  (4096x1024)
  bf16* kbuf  = (bf16*)(ws + (40ull << 20));       // 16 MB (B,NKV,DI)
  bf16* vT    = (bf16*)(ws + (56ull << 20));       // 16 MB (B,DI,NKV) swizzled
  bf16* aout  = (bf16*)(ws + (72ull << 20));       // 8 MB  (4096x1024)

  prep_kernel<<<16384, 256, 0, stream>>>(q, ctx, qg, qb, cg, cb, qn, cn,
                                         Wq, Wkv, Wproj, Wq_b, Wkv_b, Wp_b);

  gemm_fused<<<1280, 256, 0, stream>>>(qn, Wq_b, qpb, cn, Wkv_b, kbuf, vT);

  attn_kernel<<<512, 512, 0, stream>>>(qpb, kbuf, vT, aout);

  gemm_proj<<<512, 256, 0, stream>>>(aout, Wp_b, (float*)d_out, bproj, 4096, 1024);
}

// Round 20
// 139.197 us; speedup vs baseline: 1.0276x; 1.0276x over previous
//
#include <hip/hip_runtime.h>
#include <hip/hip_bf16.h>
#include <stdint.h>

#define B_N 4
#define NQ 1024
#define NKV 2048
#define DI 1024
#define H 16
#define DH 64

using bf16 = __bf16;
typedef bf16 bf16x8 __attribute__((ext_vector_type(8)));
typedef bf16 bf16x4 __attribute__((ext_vector_type(4)));
typedef float f32x4 __attribute__((ext_vector_type(4)));

typedef const __attribute__((address_space(1))) void* gptr_t;
typedef __attribute__((address_space(3))) void* sptr_t;

// ---------- fused prep: LayerNorm (blocks 0..12287) + weight f32->bf16 (12288..16383) ----------
__global__ __launch_bounds__(256) void prep_kernel(
    const float* __restrict__ q, const float* __restrict__ ctx,
    const float* __restrict__ qg, const float* __restrict__ qb,
    const float* __restrict__ cg, const float* __restrict__ cb,
    bf16* __restrict__ qn, bf16* __restrict__ cn,
    const float* __restrict__ Wq, const float* __restrict__ Wkv, const float* __restrict__ Wproj,
    bf16* __restrict__ oq, bf16* __restrict__ okv, bf16* __restrict__ op) {
  const int blk = blockIdx.x;
  const int t = threadIdx.x;
  if (blk >= 12288) {   // ---- weight convert: 1M float4 over 4096 blocks ----
    int i = (blk - 12288) * 256 + t;
    const float* src; bf16* dst; int j;
    if (i < 262144)      { src = Wq;    dst = oq;  j = i; }
    else if (i < 786432) { src = Wkv;   dst = okv; j = i - 262144; }
    else                 { src = Wproj; dst = op;  j = i - 786432; }
    float4 v = reinterpret_cast<const float4*>(src)[j];
    bf16x4 o;
    o[0] = (bf16)v.x; o[1] = (bf16)v.y; o[2] = (bf16)v.z; o[3] = (bf16)v.w;
    reinterpret_cast<bf16x4*>(dst)[j] = o;
    return;
  }
  // ---- LayerNorm: one row per block ----
  const float* x; const float* gamma; const float* beta; bf16* out; int r;
  if (blk < 4096) { x = q;   gamma = qg; beta = qb; out = qn; r = blk; }
  else            { x = ctx; gamma = cg; beta = cb; out = cn; r = blk - 4096; }
  const float4 v = reinterpret_cast<const float4*>(x + (size_t)r * 1024)[t];
  float s = v.x + v.y + v.z + v.w;
  float s2 = v.x*v.x + v.y*v.y + v.z*v.z + v.w*v.w;
#pragma unroll
  for (int m = 1; m < 64; m <<= 1) { s += __shfl_xor(s, m); s2 += __shfl_xor(s2, m); }
  __shared__ float red[8];
  int wid = t >> 6;
  if ((t & 63) == 0) { red[wid] = s; red[wid + 4] = s2; }
  __syncthreads();
  float ts  = red[0] + red[1] + red[2] + red[3];
  float ts2 = red[4] + red[5] + red[6] + red[7];
  float mean = ts * (1.0f / 1024.0f);
  float var  = ts2 * (1.0f / 1024.0f) - mean * mean;
  float rstd = rsqrtf(var + 1e-5f);
  float4 g  = reinterpret_cast<const float4*>(gamma)[t];
  float4 bb = reinterpret_cast<const float4*>(beta)[t];
  bf16x4 o;
  o[0] = (bf16)((v.x - mean) * rstd * g.x + bb.x);
  o[1] = (bf16)((v.y - mean) * rstd * g.y + bb.y);
  o[2] = (bf16)((v.z - mean) * rstd * g.z + bb.z);
  o[3] = (bf16)((v.w - mean) * rstd * g.w + bb.w);
  reinterpret_cast<bf16x4*>(out + (size_t)r * 1024)[t] = o;
}

// ---------------- GEMM body (r10-proven): 128 x BN, BK=64, 2-phase ----------------
// stage -> sync -> 2x(8 ds_read + 16 MFMA) -> sync. XOR swizzle sw=l15&7 (0-conflict).
// MODE 0: bf16 out * (0.125*log2e) | MODE 1: kv split K + V^T-permuted | MODE 2: f32+bias
template<int MODE, int BN>
__device__ __forceinline__ void gemm_body(bf16* lA, bf16* lB,
    const bf16* __restrict__ A, const bf16* __restrict__ Bm,
    void* __restrict__ out0, void* __restrict__ out1,
    const float* __restrict__ bias, int M, int N, int bid) {
  constexpr int K = 1024;
  constexpr int MI = (BN == 128) ? 4 : 2;
  constexpr int NBL = (BN == 128) ? 4 : 2;
  const int nbn = N / BN;
  const int bm = bid / nbn, bn = bid - bm * nbn;
  const int m0 = bm << 7, n0 = bn * BN;
  const int tid = threadIdx.x;
  const int lane = tid & 63, wid = tid >> 6;
  const int rowb = (BN == 128) ? ((wid >> 1) * 64) : (wid * 32);
  const int colb = (BN == 128) ? ((wid & 1) * 64) : 0;
  const int l15 = lane & 15, lg = lane >> 4;

  f32x4 acc[MI][4] = {};

  const bf16* gA[4]; const bf16* gB[NBL];
#pragma unroll
  for (int u = 0; u < 4; ++u) {
    int s = tid + u * 256;
    int row = s >> 3, c8 = (s & 7) ^ (row & 7);
    gA[u] = A + (size_t)(m0 + row) * K + c8 * 8;
  }
#pragma unroll
  for (int u = 0; u < NBL; ++u) {
    int s = tid + u * 256;
    int row = s >> 3, c8 = (s & 7) ^ (row & 7);
    gB[u] = Bm + (size_t)(n0 + row) * K + c8 * 8;
  }

  const int sw = l15 & 7;

  for (int k0 = 0; k0 < K; k0 += 64) {
#pragma unroll
    for (int u = 0; u < 4; ++u)
      __builtin_amdgcn_global_load_lds((gptr_t)(gA[u] + k0), (sptr_t)(lA + (tid + u * 256) * 8), 16, 0, 0);
#pragma unroll
    for (int u = 0; u < NBL; ++u)
      __builtin_amdgcn_global_load_lds((gptr_t)(gB[u] + k0), (sptr_t)(lB + (tid + u * 256) * 8), 16, 0, 0);
    __syncthreads();
#pragma unroll
    for (int ks2 = 0; ks2 < 2; ++ks2) {
      const int soff = ((ks2 * 4 + lg) ^ sw) * 8;
      bf16x8 af[MI], bfr[4];
#pragma unroll
      for (int i = 0; i < MI; ++i)
        af[i]  = *reinterpret_cast<const bf16x8*>(lA + (rowb + i * 16 + l15) * 64 + soff);
#pragma unroll
      for (int j = 0; j < 4; ++j)
        bfr[j] = *reinterpret_cast<const bf16x8*>(lB + (colb + j * 16 + l15) * 64 + soff);
#pragma unroll
      for (int i = 0; i < MI; ++i)
#pragma unroll
        for (int j = 0; j < 4; ++j)
          acc[i][j] = __builtin_amdgcn_mfma_f32_16x16x32_bf16(af[i], bfr[j], acc[i][j], 0, 0, 0);
    }
    __syncthreads();
  }

  const int mB = m0 + rowb + lg * 4;
  const int nB = n0 + colb + l15;
  if constexpr (MODE == 0) {
    bf16* o = reinterpret_cast<bf16*>(out0);
    constexpr float SC = 0.125f * 1.44269504089f;  // DH^-0.5 * log2(e)
#pragma unroll
    for (int i = 0; i < MI; ++i)
#pragma unroll
      for (int j = 0; j < 4; ++j)
#pragma unroll
        for (int r = 0; r < 4; ++r)
          o[(size_t)(mB + i * 16 + r) * N + nB + j * 16] = (bf16)(acc[i][j][r] * SC);
  } else if constexpr (MODE == 2) {
    float* o = reinterpret_cast<float*>(out0);
#pragma unroll
    for (int j = 0; j < 4; ++j) {
      float bj = bias[nB + j * 16];
#pragma unroll
      for (int i = 0; i < MI; ++i)
#pragma unroll
        for (int r = 0; r < 4; ++r)
          o[(size_t)(mB + i * 16 + r) * N + nB + j * 16] = acc[i][j][r] + bj;
    }
  } else {
    if (n0 < 1024) {  // K part: (B,NKV,DI)
      bf16* o = reinterpret_cast<bf16*>(out0);
#pragma unroll
      for (int i = 0; i < MI; ++i)
#pragma unroll
        for (int j = 0; j < 4; ++j)
#pragma unroll
          for (int r = 0; r < 4; ++r)
            o[(size_t)(mB + i * 16 + r) * 1024 + nB + j * 16] = (bf16)acc[i][j][r];
    } else {          // V part: transposed (B,DI,NKV) with in-64 column swizzle
      bf16* o = reinterpret_cast<bf16*>(out1);
#pragma unroll
      for (int i = 0; i < MI; ++i) {
        int m = mB + i * 16;
        int bb_ = m >> 11, kv = m & 2047;
        int u = kv & 63;
        int c = (u & 32) | ((u & 12) << 1) | ((u & 16) >> 2) | (u & 3);
        int col = (kv & ~63) | c;
#pragma unroll
        for (int j = 0; j < 4; ++j) {
          int nv = nB + j * 16 - 1024;
          bf16x4 pk;
          pk[0] = (bf16)acc[i][j][0]; pk[1] = (bf16)acc[i][j][1];
          pk[2] = (bf16)acc[i][j][2]; pk[3] = (bf16)acc[i][j][3];
          *reinterpret_cast<bf16x4*>(o + ((size_t)(bb_ << 10) + nv) * 2048 + col) = pk;
        }
      }
    }
  }
}

// Merged qp + kv GEMM: blocks [0,1024) = kv (MODE 1), [1024,1280) = qp (MODE 0, BN=128).
__global__ __launch_bounds__(256) void gemm_fused(
    const bf16* __restrict__ qn, const bf16* __restrict__ Wq, void* __restrict__ qpb,
    const bf16* __restrict__ cn, const bf16* __restrict__ Wkv,
    void* __restrict__ kbuf, void* __restrict__ vT) {
  __shared__ bf16 lA[128 * 64];
  __shared__ bf16 lB[128 * 64];
  if (blockIdx.x < 1024) {
    int rb = blockIdx.x;
    int bid = (rb & 7) * 128 + (rb >> 3);
    gemm_body<1, 128>(lA, lB, cn, Wkv, kbuf, vT, nullptr, 8192, 2048, bid);
  } else {
    int rb = blockIdx.x - 1024;
    int bid = (rb & 7) * 32 + (rb >> 3);
    gemm_body<0, 128>(lA, lB, qn, Wq, qpb, nullptr, nullptr, 4096, 1024, bid);
  }
}

// ---------------- proj GEMM (r10-proven): 128 x 64, BK=64 ----------------
__global__ __launch_bounds__(256) void gemm_proj(const bf16* __restrict__ A,
    const bf16* __restrict__ Bm, float* __restrict__ out0,
    const float* __restrict__ bias, int M, int N) {
  constexpr int K = 1024;
  __shared__ bf16 lA[128 * 64];
  __shared__ bf16 lB[64 * 64];
  const int cpx = gridDim.x >> 3;
  const int bid = (blockIdx.x & 7) * cpx + (blockIdx.x >> 3);
  const int nbn = N >> 6;
  const int bm = bid / nbn, bn = bid - bm * nbn;
  const int m0 = bm << 7, n0 = bn << 6;
  const int tid = threadIdx.x;
  const int lane = tid & 63, wid = tid >> 6;
  const int rowb = wid * 32;
  const int l15 = lane & 15, lg = lane >> 4;

  f32x4 acc[2][4] = {};

  const bf16* gA[4]; const bf16* gB[2];
#pragma unroll
  for (int u = 0; u < 4; ++u) {
    int s = tid + u * 256;
    int row = s >> 3, c8 = (s & 7) ^ (row & 7);
    gA[u] = A + (size_t)(m0 + row) * K + c8 * 8;
  }
#pragma unroll
  for (int u = 0; u < 2; ++u) {
    int s = tid + u * 256;
    int row = s >> 3, c8 = (s & 7) ^ (row & 7);
    gB[u] = Bm + (size_t)(n0 + row) * K + c8 * 8;
  }
  const int sw = l15 & 7;

  for (int k0 = 0; k0 < K; k0 += 64) {
#pragma unroll
    for (int u = 0; u < 4; ++u)
      __builtin_amdgcn_global_load_lds((gptr_t)(gA[u] + k0), (sptr_t)(lA + (tid + u * 256) * 8), 16, 0, 0);
#pragma unroll
    for (int u = 0; u < 2; ++u)
      __builtin_amdgcn_global_load_lds((gptr_t)(gB[u] + k0), (sptr_t)(lB + (tid + u * 256) * 8), 16, 0, 0);
    __syncthreads();
#pragma unroll
    for (int ks2 = 0; ks2 < 2; ++ks2) {
      const int soff = ((ks2 * 4 + lg) ^ sw) * 8;
      bf16x8 af[2], bfr[4];
#pragma unroll
      for (int i = 0; i < 2; ++i)
        af[i]  = *reinterpret_cast<const bf16x8*>(lA + (rowb + i * 16 + l15) * 64 + soff);
#pragma unroll
      for (int j = 0; j < 4; ++j)
        bfr[j] = *reinterpret_cast<const bf16x8*>(lB + (j * 16 + l15) * 64 + soff);
#pragma unroll
      for (int i = 0; i < 2; ++i)
#pragma unroll
        for (int j = 0; j < 4; ++j)
          acc[i][j] = __builtin_amdgcn_mfma_f32_16x16x32_bf16(af[i], bfr[j], acc[i][j], 0, 0, 0);
    }
    __syncthreads();
  }

  const int mB = m0 + rowb + lg * 4;
  const int nB = n0 + l15;
#pragma unroll
  for (int j = 0; j < 4; ++j) {
    float bj = bias[nB + j * 16];
#pragma unroll
    for (int i = 0; i < 2; ++i)
#pragma unroll
      for (int r = 0; r < 4; ++r)
        out0[(size_t)(mB + i * 16 + r) * N + nB + j * 16] = acc[i][j][r] + bj;
  }
}

// ---------------- Flash attention v9 (r17-proven): ones-MFMA row-sum + max3 tree ----------------
__global__ __launch_bounds__(512, 4) void attn_kernel(const bf16* __restrict__ qp,
    const bf16* __restrict__ kk, const bf16* __restrict__ vTp, bf16* __restrict__ out) {
  __shared__ bf16 smem[32768];   // [K dbuf 2x8192][V dbuf 2x8192]  (64 KB)
  const int pos = blockIdx.x;
  const int idx = pos >> 3;
  const int bh = ((idx >> 3) << 3) | (pos & 7);
  const int qt = idx & 7;
  const int b = bh >> 4, h = bh & 15;
  const int tid = threadIdx.x;              // 0..511
  const int lane = tid & 63, w = tid >> 6;  // 8 waves
  const int l15 = lane & 15, lg = lane >> 4;

  const bf16* Qb = qp + (size_t)(b * NQ + qt * 128 + w * 16) * DI + h * DH;
  const bf16* Kb = kk + (size_t)b * NKV * DI + h * DH;
  const bf16* Vb = vTp + (size_t)(b * DI + h * DH) * NKV;

  const int sA = tid, sB = tid + 512;
  const int rKA = ((sA >> 7) << 4) | (sA & 15), cKA = ((sA >> 4) & 7) * 8;
  const int rKB = ((sB >> 7) << 4) | (sB & 15), cKB = ((sB >> 4) & 7) * 8;
  const int rVA = ((sA >> 8) << 4) | (sA & 15), cVA = ((sA >> 6) & 3) * 32 + ((sA >> 4) & 3) * 8;
  const int rVB = ((sB >> 8) << 4) | (sB & 15), cVB = ((sB >> 6) & 3) * 32 + ((sB >> 4) & 3) * 8;
  const bf16* pKA = Kb + (size_t)rKA * DI + cKA;
  const bf16* pKB = Kb + (size_t)rKB * DI + cKB;
  const bf16* pVA = Vb + (size_t)rVA * NKV + cVA;
  const bf16* pVB = Vb + (size_t)rVB * NKV + cVB;

#define STAGE_KV(bufsel, kv)                                                                        \
  do {                                                                                              \
    __builtin_amdgcn_global_load_lds((gptr_t)(pKA + (size_t)(kv) * DI),                             \
                                     (sptr_t)(smem + (bufsel) * 8192 + sA * 8), 16, 0, 0);          \
    __builtin_amdgcn_global_load_lds((gptr_t)(pKB + (size_t)(kv) * DI),                             \
                                     (sptr_t)(smem + (bufsel) * 8192 + sB * 8), 16, 0, 0);          \
    __builtin_amdgcn_global_load_lds((gptr_t)(pVA + (kv)),                                          \
                                     (sptr_t)(smem + 16384 + (bufsel) * 8192 + sA * 8), 16, 0, 0);  \
    __builtin_amdgcn_global_load_lds((gptr_t)(pVB + (kv)),                                          \
                                     (sptr_t)(smem + 16384 + (bufsel) * 8192 + sB * 8), 16, 0, 0);  \
  } while (0)

  bf16x8 qf[2];
#pragma unroll
  for (int ks = 0; ks < 2; ++ks)
    qf[ks] = *reinterpret_cast<const bf16x8*>(Qb + (size_t)l15 * DI + ks * 32 + lg * 8);

  bf16x8 onesf;
#pragma unroll
  for (int jj = 0; jj < 8; ++jj) onesf[jj] = (bf16)1.0f;

  f32x4 o[4] = {};
  f32x4 lacc = {};
  float mrun = -1e30f;

  STAGE_KV(0, 0);
  __syncthreads();
  int cur = 0;

  for (int kv0 = 0; kv0 < NKV; kv0 += 128) {
    const bool notlast = (kv0 + 128 < NKV);
    if (notlast) STAGE_KV(cur ^ 1, kv0 + 128);

    const bf16* Kl = smem + cur * 8192;
    const bf16* Vl = smem + 16384 + cur * 8192;

    f32x4 s[8] = {};
#pragma unroll
    for (int h2 = 0; h2 < 2; ++h2) {
      bf16x8 kf[4][2];
#pragma unroll
      for (int ni = 0; ni < 4; ++ni)
#pragma unroll
        for (int ks = 0; ks < 2; ++ks)
          kf[ni][ks] = *reinterpret_cast<const bf16x8*>(Kl + (((h2 * 4 + ni) * 2 + ks) * 64 + lane) * 8);
      __builtin_amdgcn_s_setprio(1);
#pragma unroll
      for (int ni = 0; ni < 4; ++ni)
#pragma unroll
        for (int ks = 0; ks < 2; ++ks)
          s[h2 * 4 + ni] = __builtin_amdgcn_mfma_f32_16x16x32_bf16(kf[ni][ks], qf[ks], s[h2 * 4 + ni], 0, 0, 0);
      __builtin_amdgcn_s_setprio(0);
    }

    // ---- row max (max3-fused tree; per q = l15) ----
    float pmr[4];
#pragma unroll
    for (int r = 0; r < 4; ++r) {
      float a = fmaxf(fmaxf(s[0][r], s[1][r]), s[2][r]);
      a = fmaxf(fmaxf(a, s[3][r]), s[4][r]);
      a = fmaxf(fmaxf(a, s[5][r]), s[6][r]);
      pmr[r] = fmaxf(a, s[7][r]);
    }
    float pm = fmaxf(fmaxf(pmr[0], pmr[1]), fmaxf(pmr[2], pmr[3]));
    pm = fmaxf(pm, __shfl_xor(pm, 16));
    pm = fmaxf(pm, __shfl_xor(pm, 32));

    const bool noresc = __all(pm <= mrun);   // exact: corr == 1 when no new max
    const float mnew = noresc ? mrun : fmaxf(mrun, pm);

#pragma unroll
    for (int i = 0; i < 8; ++i)
#pragma unroll
      for (int r = 0; r < 4; ++r)
        s[i][r] = __builtin_amdgcn_exp2f(s[i][r] - mnew);

    if (!noresc) {
      float corr = __builtin_amdgcn_exp2f(mrun - mnew);
      mrun = mnew;
      float c0 = __shfl(corr, lg * 4 + 0);
      float c1 = __shfl(corr, lg * 4 + 1);
      float c2 = __shfl(corr, lg * 4 + 2);
      float c3 = __shfl(corr, lg * 4 + 3);
      lacc[0] *= c0; lacc[1] *= c1; lacc[2] *= c2; lacc[3] *= c3;
#pragma unroll
      for (int dt = 0; dt < 4; ++dt) {
        o[dt][0] *= c0; o[dt][1] *= c1; o[dt][2] *= c2; o[dt][3] *= c3;
      }
    }

    // ---- pack P (register-only): pa[k2], k2 = h2*2 + k2' ----
    bf16x8 pa[4];
#pragma unroll
    for (int h2 = 0; h2 < 2; ++h2)
#pragma unroll
      for (int k2p = 0; k2p < 2; ++k2p)
#pragma unroll
        for (int jj = 0; jj < 4; ++jj) {
          pa[h2 * 2 + k2p][jj]     = (bf16)s[h2 * 4 + k2p * 2 + 0][jj];
          pa[h2 * 2 + k2p][4 + jj] = (bf16)s[h2 * 4 + k2p * 2 + 1][jj];
        }

    // ---- PV + row-sum, all on the matrix pipe ----
    __builtin_amdgcn_s_setprio(1);
#pragma unroll
    for (int k2 = 0; k2 < 4; ++k2) {
      bf16x8 vf[4];
#pragma unroll
      for (int dt = 0; dt < 4; ++dt)
        vf[dt] = *reinterpret_cast<const bf16x8*>(Vl + ((dt * 4 + k2) * 64 + lane) * 8);
#pragma unroll
      for (int dt = 0; dt < 4; ++dt)
        o[dt] = __builtin_amdgcn_mfma_f32_16x16x32_bf16(pa[k2], vf[dt], o[dt], 0, 0, 0);
      lacc = __builtin_amdgcn_mfma_f32_16x16x32_bf16(pa[k2], onesf, lacc, 0, 0, 0);
    }
    __builtin_amdgcn_s_setprio(0);

    if (notlast) __syncthreads();
    cur ^= 1;
  }
#undef STAGE_KV

  // epilogue: lacc already holds per-(lg,r) row sums in O-layout -> no shuffles
  const float iv0 = 1.0f / lacc[0];
  const float iv1 = 1.0f / lacc[1];
  const float iv2 = 1.0f / lacc[2];
  const float iv3 = 1.0f / lacc[3];

  bf16* Ob = out + (size_t)(b * NQ + qt * 128 + w * 16) * DI + h * DH;
#pragma unroll
  for (int dt = 0; dt < 4; ++dt) {
    Ob[(size_t)(lg * 4 + 0) * DI + dt * 16 + l15] = (bf16)(o[dt][0] * iv0);
    Ob[(size_t)(lg * 4 + 1) * DI + dt * 16 + l15] = (bf16)(o[dt][1] * iv1);
    Ob[(size_t)(lg * 4 + 2) * DI + dt * 16 + l15] = (bf16)(o[dt][2] * iv2);
    Ob[(size_t)(lg * 4 + 3) * DI + dt * 16 + l15] = (bf16)(o[dt][3] * iv3);
  }
}

// ---------------- launch ----------------
extern "C" void kernel_launch(void* const* d_in, const int* in_sizes, int n_in,
                              void* d_out, int out_size, void* d_ws, size_t ws_size,
                              hipStream_t stream) {
  const float* q     = (const float*)d_in[0];
  const float* ctx   = (const float*)d_in[1];
  const float* Wq    = (const float*)d_in[2];
  const float* Wkv   = (const float*)d_in[3];
  const float* Wproj = (const float*)d_in[4];
  const float* bproj = (const float*)d_in[5];
  const float* qg    = (const float*)d_in[6];
  const float* qb    = (const float*)d_in[7];
  const float* cg    = (const float*)d_in[8];
  const float* cb    = (const float*)d_in[9];

  char* ws = (char*)d_ws;
  bf16* qn    = (bf16*)(ws);                       // 8 MB  (4096x1024)
  bf16* cn    = (bf16*)(ws + ( 8ull << 20));       // 16 MB (8192x1024)
  bf16* Wq_b  = (bf16*)(ws + (24ull << 20));       // 2 MB
  bf16* Wkv_b = (bf16*)(ws + (26ull << 20));       // 4 MB
  bf16* Wp_b  = (bf16*)(ws + (30ull << 20));       // 2 MB
  bf16* qpb   = (bf16*)(ws + (32ull << 20));       // 8 MB  (4096x1024)
  bf16* kbuf  = (bf16*)(ws + (40ull << 20));       // 16 MB (B,NKV,DI)
  bf16* vT    = (bf16*)(ws + (56ull << 20));       // 16 MB (B,DI,NKV) swizzled
  bf16* aout  = (bf16*)(ws + (72ull << 20));       // 8 MB  (4096x1024)

  prep_kernel<<<16384, 256, 0, stream>>>(q, ctx, qg, qb, cg, cb, qn, cn,
                                         Wq, Wkv, Wproj, Wq_b, Wkv_b, Wp_b);

  gemm_fused<<<1280, 256, 0, stream>>>(qn, Wq_b, qpb, cn, Wkv_b, kbuf, vT);

  attn_kernel<<<512, 512, 0, stream>>>(qpb, kbuf, vT, aout);

  gemm_proj<<<512, 256, 0, stream>>>(aout, Wp_b, (float*)d_out, bproj, 4096, 1024);
}